// Round 14
// baseline (176.319 us; speedup 1.0000x reference)
//
#include <hip/hip_runtime.h>
#include <stdint.h>

typedef unsigned short u16;
typedef __attribute__((ext_vector_type(8))) short bf16x8;
typedef __attribute__((ext_vector_type(4))) float f32x4;

__device__ __forceinline__ u16 f2bf(float f) {
    union { float f; uint32_t u; } v; v.f = f;
    uint32_t u = v.u + 0x7fffu + ((v.u >> 16) & 1u);
    return (u16)(u >> 16);
}
// hardware 2^x
__device__ __forceinline__ float vexp2(float x) {
    float d;
    asm("v_exp_f32 %0, %1" : "=v"(d) : "v"(x));
    return d;
}
// packed f32x2 -> bf16x2 (hardware round)
__device__ __forceinline__ uint32_t cvtpk(float a, float b) {
    uint32_t d;
    asm("v_cvt_pk_bf16_f32 %0, %1, %2" : "=v"(d) : "v"(a), "v"(b));
    return d;
}

__device__ __forceinline__ void gld16(const void* g, void* l) {
    __builtin_amdgcn_global_load_lds((const __attribute__((address_space(1))) void*)g,
                                     (__attribute__((address_space(3))) void*)l,
                                     16, 0, 0);
}

// in-place cross-lane swap: a.row1<->b.row0, a.row3<->b.row2 (rows = 16-lane groups)
__device__ __forceinline__ void plswap16(uint32_t& a, uint32_t& b) {
    asm volatile("v_permlane16_swap_b32 %0, %1" : "+v"(a), "+v"(b));
}

// ---------------- fused pack kernel: 4 weight transposes + x cvt ----------------
// grid (32,32,5), block (32,8). z<4: transpose W_z. z==4: x fp32->bf16 stream.

__global__ void pack5_kernel(const float* __restrict__ Wq, const float* __restrict__ Wk,
                             const float* __restrict__ Wv, const float* __restrict__ Wo,
                             const float* __restrict__ x,
                             u16* __restrict__ dqkv, u16* __restrict__ dwo,
                             u16* __restrict__ dx) {
    const int z = blockIdx.z;
    const int tx = threadIdx.x, ty = threadIdx.y;
    if (z == 4) {
        // x cvt: 1024 blocks x 1024 float4
        const int bid = blockIdx.y * 32 + blockIdx.x;
        const int tid = ty * 32 + tx;
#pragma unroll
        for (int i = 0; i < 4; ++i) {
            const int idx = bid * 1024 + i * 256 + tid;
            float4 v = ((const float4*)x)[idx];
            ushort4 o;
            o.x = f2bf(v.x); o.y = f2bf(v.y); o.z = f2bf(v.z); o.w = f2bf(v.w);
            ((ushort4*)dx)[idx] = o;
        }
        return;
    }
    __shared__ float tile[32][33];
    const float* src = (z == 0) ? Wq : (z == 1) ? Wk : (z == 2) ? Wv : Wo;
    u16* dst = (z < 3) ? (dqkv + (size_t)z * 1024 * 1024) : dwo;
    const int bx = blockIdx.x * 32, by = blockIdx.y * 32;
#pragma unroll
    for (int i = ty; i < 32; i += 8)
        tile[i][tx] = src[(size_t)(by + i) * 1024 + bx + tx];
    __syncthreads();
#pragma unroll
    for (int i = ty; i < 32; i += 8)
        dst[(size_t)(bx + i) * 1024 + by + tx] = f2bf(tile[tx][i]);
}

// ---------------- GEMM (128x128 tile, BK=64, double-buffered, counted vmcnt) ----------------
// 1D grid with bijective XCD swizzle. nbx = N/128 column-blocks.
// Per K-step: issue next tile's 8 gld16, wait vmcnt(8) (keeps them in flight),
// raw barrier, compute 2 kk sub-steps, raw barrier. No in-loop vmcnt(0) drain.

#define GEMM_STEP(CUR, K0N, PREF, WAITN)                                              \
    {                                                                                 \
        if (PREF) {                                                                   \
            _Pragma("unroll")                                                         \
            for (int i = 0; i < 4; ++i) {                                             \
                const int idx = i * 256 + t;                                          \
                const int row = idx >> 3, ch = idx & 7;                               \
                const int chg = ch ^ (row & 7);                                       \
                gld16(A + (size_t)(mbase + row) * 1024 + (K0N) + chg * 8,             \
                      (char*)&As[CUR ^ 1][0] + idx * 16);                             \
                gld16(Bt + (size_t)(nbase + row) * 1024 + (K0N) + chg * 8,            \
                      (char*)&Bs[CUR ^ 1][0] + idx * 16);                             \
            }                                                                         \
        }                                                                             \
        asm volatile("s_waitcnt vmcnt(" #WAITN ")" ::: "memory");                     \
        __builtin_amdgcn_s_barrier();                                                 \
        __builtin_amdgcn_sched_barrier(0);                                            \
        _Pragma("unroll")                                                             \
        for (int kk = 0; kk < 2; ++kk) {                                              \
            bf16x8 af[4], bfr[4];                                                     \
            _Pragma("unroll")                                                         \
            for (int m = 0; m < 4; ++m)                                               \
                af[m] = *(const bf16x8*)((const char*)&As[CUR][0] +                   \
                        (wm * 64 + m * 16 + r) * 128 + (((kk * 4 + g) ^ sw) << 4));   \
            _Pragma("unroll")                                                         \
            for (int n = 0; n < 4; ++n)                                               \
                bfr[n] = *(const bf16x8*)((const char*)&Bs[CUR][0] +                  \
                        (wn * 64 + n * 16 + r) * 128 + (((kk * 4 + g) ^ sw) << 4));   \
            __builtin_amdgcn_s_setprio(1);                                            \
            _Pragma("unroll")                                                         \
            for (int m = 0; m < 4; ++m)                                               \
                _Pragma("unroll")                                                     \
                for (int n = 0; n < 4; ++n)                                           \
                    acc[m][n] = __builtin_amdgcn_mfma_f32_16x16x32_bf16(              \
                        af[m], bfr[n], acc[m][n], 0, 0, 0);                           \
            __builtin_amdgcn_s_setprio(0);                                            \
        }                                                                             \
        __builtin_amdgcn_sched_barrier(0);                                            \
        __builtin_amdgcn_s_barrier();                                                 \
    }

template <int EPI>
__global__ __launch_bounds__(256) void gemm128(
    const u16* __restrict__ A, const u16* __restrict__ Bt,
    const float* __restrict__ bias0, const float* __restrict__ bias1,
    const float* __restrict__ bias2,
    u16* __restrict__ o_q, u16* __restrict__ o_k, u16* __restrict__ o_vt,
    float* __restrict__ o_f, int nbx)
{
    __shared__ u16 As[2][128 * 64];   // 16 KB per buf; rows of 128 B, swizzle ch^(row&7)
    __shared__ u16 Bs[2][128 * 64];
    const int t = threadIdx.x;
    const int lane = t & 63, w = t >> 6;
    const int wm = w >> 1, wn = w & 1;
    const int g = lane >> 4, r = lane & 15;
    const int sw = r & 7;
    // bijective XCD swizzle (grid % 8 == 0)
    const int f = blockIdx.x;
    const int cpx = (gridDim.x >> 3);
    const int swz = (f & 7) * cpx + (f >> 3);
    const int mbase = (swz / nbx) * 128, nbase = (swz % nbx) * 128;

    const f32x4 zero4 = {0.f, 0.f, 0.f, 0.f};
    f32x4 acc[4][4];
#pragma unroll
    for (int m = 0; m < 4; ++m)
#pragma unroll
        for (int n = 0; n < 4; ++n) acc[m][n] = zero4;

    // prologue: stage tile 0 into buf 0 (8 gld16 in flight)
#pragma unroll
    for (int i = 0; i < 4; ++i) {
        const int idx = i * 256 + t;
        const int row = idx >> 3, ch = idx & 7;
        const int chg = ch ^ (row & 7);
        gld16(A + (size_t)(mbase + row) * 1024 + chg * 8, (char*)&As[0][0] + idx * 16);
        gld16(Bt + (size_t)(nbase + row) * 1024 + chg * 8, (char*)&Bs[0][0] + idx * 16);
    }

    int k0 = 0;
    for (int s = 0; s < 7; ++s) {
        GEMM_STEP(0, k0 + 64, 1, 8) k0 += 64;
        GEMM_STEP(1, k0 + 64, 1, 8) k0 += 64;
    }
    GEMM_STEP(0, k0 + 64, 1, 8) k0 += 64;   // step 14 (stages step 15)
    GEMM_STEP(1, 0, 0, 0)                   // step 15 (drain own loads)

#pragma unroll
    for (int m = 0; m < 4; ++m) {
#pragma unroll
        for (int n = 0; n < 4; ++n) {
            const int c = nbase + wn * 64 + n * 16 + r;
#pragma unroll
            for (int j = 0; j < 4; ++j) {
                const int rr = mbase + wm * 64 + m * 16 + g * 4 + j;
                const float y = acc[m][n][j];
                if (EPI == 0) {
                    const int which = c >> 10, d = c & 1023;
                    const int b = rr >> 11, l = rr & 2047;
                    const int h = d >> 6, dd = d & 63;
                    const size_t bh = (size_t)(b * 16 + h);
                    if (which == 0) {
                        // Q pre-scale: 1/sqrt(64) * log2(e), so attn uses exp2 directly
                        o_q[(bh * 2048 + l) * 64 + dd] = f2bf((y + bias0[d]) * 0.18033688011112042f);
                    } else if (which == 1) {
                        o_k[(bh * 2048 + l) * 64 + dd] = f2bf(y + bias1[d]);
                    } else {
                        o_vt[(bh * 64 + dd) * 2048 + l] = f2bf(y + bias2[d]);
                    }
                } else {
                    o_f[(size_t)rr * 1024 + c] = y + bias0[c];
                }
            }
        }
    }
}

// ---------------- flash attention v11 (unchanged from R12) ----------------
// grid: 1024 flat. XCD x = flat&7 owns batch (x>>2), q-tiles (x&3)*8..+7, ALL 16 heads.
// block: 128 (2 waves x 32 q-rows). Counted vmcnt, raw barriers, no in-loop drain.

#define ATTN_STEP(CUR, BD, BDN, PREF, WAITN)                                                 \
    {                                                                                        \
        if (PREF) {                                                                          \
            const int kt2 = kt + 64;                                                         \
            _Pragma("unroll")                                                                \
            for (int i = 0; i < 4; ++i) {                                                    \
                const int idx = i * 128 + t;                                                 \
                const int row = idx >> 3, ch = idx & 7;                                      \
                const int chg = ch ^ (row & 7);                                              \
                gld16(kb + kvBase + (size_t)(kt2 + row) * 64 + chg * 8,                      \
                      (char*)&Ks[CUR ^ 1][0] + idx * 16);                                    \
                gld16(vtb + vtBase + (size_t)row * 2048 + kt2 + chg * 8,                     \
                      (char*)&Vs[CUR ^ 1][0] + idx * 16);                                    \
            }                                                                                \
            _Pragma("unroll")                                                                \
            for (int qf = 0; qf < 2; ++qf)                                                   \
                _Pragma("unroll")                                                            \
                for (int kf = 0; kf < 4; ++kf)                                               \
                    BDN[qf][kf] = *(const float4*)&bondf[bondRow0 + (size_t)qf * 32768 +     \
                                                         kt2 + kf * 16 + g * 4];             \
        }                                                                                    \
        asm volatile("s_waitcnt vmcnt(" #WAITN ")" ::: "memory");                            \
        __builtin_amdgcn_s_barrier();                                                        \
        __builtin_amdgcn_sched_barrier(0);                                                   \
        /* QK^T kf=0,1 */                                                                    \
        f32x4 st[2][4];                                                                      \
        {                                                                                    \
            bf16x8 kfr[2][2];                                                                \
            _Pragma("unroll")                                                                \
            for (int kz = 0; kz < 2; ++kz)                                                   \
                _Pragma("unroll")                                                            \
                for (int kf = 0; kf < 2; ++kf)                                               \
                    kfr[kz][kf] = *(const bf16x8*)((const char*)&Ks[CUR][0] +                \
                                    (kf * 16 + r) * 128 + (((kz * 4 + g) ^ sw) * 16));       \
            _Pragma("unroll")                                                                \
            for (int qf = 0; qf < 2; ++qf)                                                   \
                _Pragma("unroll")                                                            \
                for (int kf = 0; kf < 2; ++kf) st[qf][kf] = zero4;                           \
            __builtin_amdgcn_s_setprio(1);                                                   \
            _Pragma("unroll")                                                                \
            for (int kz = 0; kz < 2; ++kz)                                                   \
                _Pragma("unroll")                                                            \
                for (int qf = 0; qf < 2; ++qf)                                               \
                    _Pragma("unroll")                                                        \
                    for (int kf = 0; kf < 2; ++kf)                                           \
                        st[qf][kf] = __builtin_amdgcn_mfma_f32_16x16x32_bf16(                \
                            kfr[kz][kf], aq[qf][kz], st[qf][kf], 0, 0, 0);                   \
            __builtin_amdgcn_s_setprio(0);                                                   \
        }                                                                                    \
        /* exp kf=0,1 -> ap0 */                                                              \
        bf16x8 ap0[2], ap1[2];                                                               \
        _Pragma("unroll")                                                                    \
        for (int qf = 0; qf < 2; ++qf) {                                                     \
            uint32_t pkl[2], pkh[2];                                                         \
            _Pragma("unroll")                                                                \
            for (int kf = 0; kf < 2; ++kf) {                                                 \
                const float p0 = vexp2(st[qf][kf][0] * BD[qf][kf].x);                        \
                const float p1 = vexp2(st[qf][kf][1] * BD[qf][kf].y);                        \
                const float p2 = vexp2(st[qf][kf][2] * BD[qf][kf].z);                        \
                const float p3 = vexp2(st[qf][kf][3] * BD[qf][kf].w);                        \
                sm[qf] += (p0 + p1) + (p2 + p3);                                             \
                pkl[kf] = cvtpk(p0, p1);                                                     \
                pkh[kf] = cvtpk(p2, p3);                                                     \
            }                                                                                \
            plswap16(pkl[0], pkl[1]);                                                        \
            plswap16(pkh[0], pkh[1]);                                                        \
            union { uint32_t u[4]; bf16x8 v; } a_;                                           \
            a_.u[0] = pkl[0]; a_.u[1] = pkh[0]; a_.u[2] = pkl[1]; a_.u[3] = pkh[1];          \
            ap0[qf] = a_.v;                                                                  \
        }                                                                                    \
        /* QK^T kf=2,3 */                                                                    \
        {                                                                                    \
            bf16x8 kfr[2][2];                                                                \
            _Pragma("unroll")                                                                \
            for (int kz = 0; kz < 2; ++kz)                                                   \
                _Pragma("unroll")                                                            \
                for (int kf = 0; kf < 2; ++kf)                                               \
                    kfr[kz][kf] = *(const bf16x8*)((const char*)&Ks[CUR][0] +                \
                                    ((kf + 2) * 16 + r) * 128 + (((kz * 4 + g) ^ sw) * 16)); \
            _Pragma("unroll")                                                                \
            for (int qf = 0; qf < 2; ++qf)                                                   \
                _Pragma("unroll")                                                            \
                for (int kf = 0; kf < 2; ++kf) st[qf][kf + 2] = zero4;                       \
            __builtin_amdgcn_s_setprio(1);                                                   \
            _Pragma("unroll")                                                                \
            for (int kz = 0; kz < 2; ++kz)                                                   \
                _Pragma("unroll")                                                            \
                for (int qf = 0; qf < 2; ++qf)                                               \
                    _Pragma("unroll")                                                        \
                    for (int kf = 0; kf < 2; ++kf)                                           \
                        st[qf][kf + 2] = __builtin_amdgcn_mfma_f32_16x16x32_bf16(            \
                            kfr[kz][kf], aq[qf][kz], st[qf][kf + 2], 0, 0, 0);               \
            __builtin_amdgcn_s_setprio(0);                                                   \
        }                                                                                    \
        /* PV kz=0 */                                                                        \
        {                                                                                    \
            bf16x8 bv_[4];                                                                   \
            _Pragma("unroll")                                                                \
            for (int nf = 0; nf < 4; ++nf)                                                   \
                bv_[nf] = *(const bf16x8*)((const char*)&Vs[CUR][0] +                        \
                            (nf * 16 + r) * 128 + ((pg ^ sw) * 16));                         \
            __builtin_amdgcn_s_setprio(1);                                                   \
            _Pragma("unroll")                                                                \
            for (int qf = 0; qf < 2; ++qf)                                                   \
                _Pragma("unroll")                                                            \
                for (int nf = 0; nf < 4; ++nf)                                               \
                    o[qf][nf] = __builtin_amdgcn_mfma_f32_16x16x32_bf16(                     \
                        ap0[qf], bv_[nf], o[qf][nf], 0, 0, 0);                               \
            __builtin_amdgcn_s_setprio(0);                                                   \
        }                                                                                    \
        /* exp kf=2,3 -> ap1 */                                                              \
        _Pragma("unroll")                                                                    \
        for (int qf = 0; qf < 2; ++qf) {                                                     \
            uint32_t pkl[2], pkh[2];                                                         \
            _Pragma("unroll")                                                                \
            for (int kf = 0; kf < 2; ++kf) {                                                 \
                const float p0 = vexp2(st[qf][kf + 2][0] * BD[qf][kf + 2].x);                \
                const float p1 = vexp2(st[qf][kf + 2][1] * BD[qf][kf + 2].y);                \
                const float p2 = vexp2(st[qf][kf + 2][2] * BD[qf][kf + 2].z);                \
                const float p3 = vexp2(st[qf][kf + 2][3] * BD[qf][kf + 2].w);                \
                sm[qf] += (p0 + p1) + (p2 + p3);                                             \
                pkl[kf] = cvtpk(p0, p1);                                                     \
                pkh[kf] = cvtpk(p2, p3);                                                     \
            }                                                                                \
            plswap16(pkl[0], pkl[1]);                                                        \
            plswap16(pkh[0], pkh[1]);                                                        \
            union { uint32_t u[4]; bf16x8 v; } a_;                                           \
            a_.u[0] = pkl[0]; a_.u[1] = pkh[0]; a_.u[2] = pkl[1]; a_.u[3] = pkh[1];          \
            ap1[qf] = a_.v;                                                                  \
        }                                                                                    \
        /* PV kz=1 */                                                                        \
        {                                                                                    \
            bf16x8 bv_[4];                                                                   \
            _Pragma("unroll")                                                                \
            for (int nf = 0; nf < 4; ++nf)                                                   \
                bv_[nf] = *(const bf16x8*)((const char*)&Vs[CUR][0] +                        \
                            (nf * 16 + r) * 128 + (((4 + pg) ^ sw) * 16));                   \
            __builtin_amdgcn_s_setprio(1);                                                   \
            _Pragma("unroll")                                                                \
            for (int qf = 0; qf < 2; ++qf)                                                   \
                _Pragma("unroll")                                                            \
                for (int nf = 0; nf < 4; ++nf)                                               \
                    o[qf][nf] = __builtin_amdgcn_mfma_f32_16x16x32_bf16(                     \
                        ap1[qf], bv_[nf], o[qf][nf], 0, 0, 0);                               \
            __builtin_amdgcn_s_setprio(0);                                                   \
        }                                                                                    \
        __builtin_amdgcn_sched_barrier(0);                                                   \
        __builtin_amdgcn_s_barrier();                                                        \
        kt += 64;                                                                            \
    }

__global__ __launch_bounds__(128, 2) void attn_kernel(
    const u16* __restrict__ qb, const u16* __restrict__ kb,
    const u16* __restrict__ vtb, const float* __restrict__ bondf,
    u16* __restrict__ attnout)
{
    __shared__ u16 Ks[2][64 * 64];   // [buf][key][dk]   swizzled chunks
    __shared__ u16 Vs[2][64 * 64];   // [buf][dk][key]   swizzled chunks
    const int t = threadIdx.x;
    const int lane = t & 63, w = t >> 6;
    const int g = lane >> 4, r = lane & 15;
    const int sw = r & 7;
    const int pg = ((g & 1) << 1) | (g >> 1);   // key-chunk permutation from permlane16_swap
    const int flat = blockIdx.x;
    const int x = flat & 7;          // XCD (dispatch round-robin)
    const int j = flat >> 3;         // 0..127 within XCD
    const int b = x >> 2;
    const int qt = (x & 3) * 8 + (j & 7);
    const int h = j >> 3;
    const int bh = b * 16 + h;
    const int q0 = qt * 64 + w * 32;
    const size_t kvBase = (size_t)bh * 2048 * 64;
    const size_t vtBase = (size_t)bh * 64 * 2048;
    const size_t bondRow0 = ((size_t)b * 2048 + q0 + r) * 2048;   // qf adds 32768

    // Q as B-operand fragments (pre-scaled by 1/8*log2e in the QKV epilogue)
    bf16x8 aq[2][2];
#pragma unroll
    for (int qf = 0; qf < 2; ++qf)
#pragma unroll
        for (int kz = 0; kz < 2; ++kz)
            aq[qf][kz] = *(const bf16x8*)&qb[kvBase + (size_t)(q0 + qf * 16 + r) * 64 + kz * 32 + g * 8];

    const f32x4 zero4 = {0.f, 0.f, 0.f, 0.f};
    f32x4 o[2][4];
#pragma unroll
    for (int qf = 0; qf < 2; ++qf)
#pragma unroll
        for (int nf = 0; nf < 4; ++nf) o[qf][nf] = zero4;
    float sm[2] = {0.f, 0.f};

    // prologue: stage K/V tile 0; bond tile 0 into bdA regs (16 vmem in flight)
#pragma unroll
    for (int i = 0; i < 4; ++i) {
        const int idx = i * 128 + t;
        const int row = idx >> 3, ch = idx & 7;
        const int chg = ch ^ (row & 7);
        gld16(kb + kvBase + (size_t)row * 64 + chg * 8, (char*)&Ks[0][0] + idx * 16);
        gld16(vtb + vtBase + (size_t)row * 2048 + chg * 8, (char*)&Vs[0][0] + idx * 16);
    }
    float4 bdA[2][4], bdB[2][4];
#pragma unroll
    for (int qf = 0; qf < 2; ++qf)
#pragma unroll
        for (int kf = 0; kf < 4; ++kf)
            bdA[qf][kf] = *(const float4*)&bondf[bondRow0 + (size_t)qf * 32768 + kf * 16 + g * 4];

    int kt = 0;
    for (int s = 0; s < 15; ++s) {
        ATTN_STEP(0, bdA, bdB, 1, 16)   // iters 0,2,..,28
        ATTN_STEP(1, bdB, bdA, 1, 16)   // iters 1,3,..,29
    }
    ATTN_STEP(0, bdA, bdB, 1, 16)       // iter 30 (stages tile 31)
    ATTN_STEP(1, bdB, bdA, 0, 0)        // iter 31 (drain)

    // row sums: reduce across the 4 g-groups, redistribute via width-16 shuffle
#pragma unroll
    for (int qf = 0; qf < 2; ++qf) {
        sm[qf] += __shfl_xor(sm[qf], 16, 64);
        sm[qf] += __shfl_xor(sm[qf], 32, 64);
    }
#pragma unroll
    for (int qf = 0; qf < 2; ++qf)
#pragma unroll
        for (int j2 = 0; j2 < 4; ++j2) {
            const float inv = 1.f / __shfl(sm[qf], g * 4 + j2, 16);
            const size_t orow = ((size_t)b * 2048 + q0 + qf * 16 + g * 4 + j2) * 1024 + h * 64;
#pragma unroll
            for (int nf = 0; nf < 4; ++nf)
                attnout[orow + nf * 16 + r] = f2bf(o[qf][nf][j2] * inv);
        }
}

// ---------------- launch ----------------

extern "C" void kernel_launch(void* const* d_in, const int* in_sizes, int n_in,
                              void* d_out, int out_size, void* d_ws, size_t ws_size,
                              hipStream_t stream) {
    (void)in_sizes; (void)n_in; (void)out_size; (void)ws_size;
    const float* x    = (const float*)d_in[0];
    const float* bond = (const float*)d_in[1];
    const float* Wq   = (const float*)d_in[2];
    const float* bq   = (const float*)d_in[3];
    const float* Wk   = (const float*)d_in[4];
    const float* bk   = (const float*)d_in[5];
    const float* Wv   = (const float*)d_in[6];
    const float* bv   = (const float*)d_in[7];
    const float* Wo   = (const float*)d_in[8];
    const float* bo   = (const float*)d_in[9];
    float* out = (float*)d_out;

    char* ws = (char*)d_ws;
    u16* xb      = (u16*)(ws);
    u16* wqkvt   = (u16*)(ws + 8388608);
    u16* wot     = (u16*)(ws + 14680064);
    u16* qb      = (u16*)(ws + 16777216);
    u16* kb_     = (u16*)(ws + 25165824);
    u16* vtb     = (u16*)(ws + 33554432);
    u16* attnout = (u16*)(ws + 58720256);

    pack5_kernel<<<dim3(32, 32, 5), dim3(32, 8), 0, stream>>>(Wq, Wk, Wv, Wo, x, wqkvt, wot, xb);

    gemm128<0><<<dim3(768), 256, 0, stream>>>(xb, wqkvt, bq, bk, bv, qb, kb_, vtb, nullptr, 24);
    attn_kernel<<<dim3(1024), 128, 0, stream>>>(qb, kb_, vtb, bond, attnout);
    gemm128<1><<<dim3(256), 256, 0, stream>>>(attnout, wot, bo, nullptr, nullptr,
                                              nullptr, nullptr, nullptr, out, 8);
}

// Round 15
// 159.087 us; speedup vs baseline: 1.1083x; 1.1083x over previous
//
#include <hip/hip_runtime.h>
#include <stdint.h>

typedef unsigned short u16;
typedef __attribute__((ext_vector_type(8))) short bf16x8;
typedef __attribute__((ext_vector_type(4))) float f32x4;

__device__ __forceinline__ u16 f2bf(float f) {
    union { float f; uint32_t u; } v; v.f = f;
    uint32_t u = v.u + 0x7fffu + ((v.u >> 16) & 1u);
    return (u16)(u >> 16);
}
// hardware 2^x
__device__ __forceinline__ float vexp2(float x) {
    float d;
    asm("v_exp_f32 %0, %1" : "=v"(d) : "v"(x));
    return d;
}
// packed f32x2 -> bf16x2 (hardware round)
__device__ __forceinline__ uint32_t cvtpk(float a, float b) {
    uint32_t d;
    asm("v_cvt_pk_bf16_f32 %0, %1, %2" : "=v"(d) : "v"(a), "v"(b));
    return d;
}

__device__ __forceinline__ void gld16(const void* g, void* l) {
    __builtin_amdgcn_global_load_lds((const __attribute__((address_space(1))) void*)g,
                                     (__attribute__((address_space(3))) void*)l,
                                     16, 0, 0);
}

// in-place cross-lane swap: a.row1<->b.row0, a.row3<->b.row2 (rows = 16-lane groups)
__device__ __forceinline__ void plswap16(uint32_t& a, uint32_t& b) {
    asm volatile("v_permlane16_swap_b32 %0, %1" : "+v"(a), "+v"(b));
}

// ---------------- fused pack kernel: 4 weight transposes + x cvt ----------------
// grid (32,32,5), block (32,8). z<4: transpose W_z. z==4: x fp32->bf16 stream.

__global__ void pack5_kernel(const float* __restrict__ Wq, const float* __restrict__ Wk,
                             const float* __restrict__ Wv, const float* __restrict__ Wo,
                             const float* __restrict__ x,
                             u16* __restrict__ dqkv, u16* __restrict__ dwo,
                             u16* __restrict__ dx) {
    const int z = blockIdx.z;
    const int tx = threadIdx.x, ty = threadIdx.y;
    if (z == 4) {
        // x cvt: 1024 blocks x 1024 float4
        const int bid = blockIdx.y * 32 + blockIdx.x;
        const int tid = ty * 32 + tx;
#pragma unroll
        for (int i = 0; i < 4; ++i) {
            const int idx = bid * 1024 + i * 256 + tid;
            float4 v = ((const float4*)x)[idx];
            ushort4 o;
            o.x = f2bf(v.x); o.y = f2bf(v.y); o.z = f2bf(v.z); o.w = f2bf(v.w);
            ((ushort4*)dx)[idx] = o;
        }
        return;
    }
    __shared__ float tile[32][33];
    const float* src = (z == 0) ? Wq : (z == 1) ? Wk : (z == 2) ? Wv : Wo;
    u16* dst = (z < 3) ? (dqkv + (size_t)z * 1024 * 1024) : dwo;
    const int bx = blockIdx.x * 32, by = blockIdx.y * 32;
#pragma unroll
    for (int i = ty; i < 32; i += 8)
        tile[i][tx] = src[(size_t)(by + i) * 1024 + bx + tx];
    __syncthreads();
#pragma unroll
    for (int i = ty; i < 32; i += 8)
        dst[(size_t)(bx + i) * 1024 + by + tx] = f2bf(tile[tx][i]);
}

// ---------------- GEMM (128x128 tile, BK=32, double-buffered, counted vmcnt) ----------------
// 32 KB total LDS -> 4 blocks/CU (R13 occupancy) + R10-style no-drain schedule.
// Per K-step: issue next tile's 4 gld16, wait vmcnt(4), raw barrier, 16 MFMA, raw barrier.
// 64 B LDS rows, swizzle ch ^ ((row&3)^((row>>2)&3)); read-side reduces to lane const sv.

#define GEMM_STEP(CUR, K0N, PREF, WAITN)                                              \
    {                                                                                 \
        if (PREF) {                                                                   \
            _Pragma("unroll")                                                         \
            for (int i = 0; i < 2; ++i) {                                             \
                const int idx = i * 256 + t;                                          \
                const int row = idx >> 2, ch = idx & 3;                               \
                const int chg = ch ^ ((row & 3) ^ ((row >> 2) & 3));                  \
                gld16(A + (size_t)(mbase + row) * 1024 + (K0N) + chg * 8,             \
                      (char*)&As[CUR ^ 1][0] + idx * 16);                             \
                gld16(Bt + (size_t)(nbase + row) * 1024 + (K0N) + chg * 8,            \
                      (char*)&Bs[CUR ^ 1][0] + idx * 16);                             \
            }                                                                         \
        }                                                                             \
        asm volatile("s_waitcnt vmcnt(" #WAITN ")" ::: "memory");                     \
        __builtin_amdgcn_s_barrier();                                                 \
        __builtin_amdgcn_sched_barrier(0);                                            \
        bf16x8 af[4], bfr[4];                                                         \
        _Pragma("unroll")                                                             \
        for (int m = 0; m < 4; ++m)                                                   \
            af[m] = *(const bf16x8*)((const char*)&As[CUR][0] +                       \
                    (wm * 64 + m * 16 + r) * 64 + ((g ^ sv) << 4));                   \
        _Pragma("unroll")                                                             \
        for (int n = 0; n < 4; ++n)                                                   \
            bfr[n] = *(const bf16x8*)((const char*)&Bs[CUR][0] +                      \
                    (wn * 64 + n * 16 + r) * 64 + ((g ^ sv) << 4));                   \
        __builtin_amdgcn_s_setprio(1);                                                \
        _Pragma("unroll")                                                             \
        for (int m = 0; m < 4; ++m)                                                   \
            _Pragma("unroll")                                                         \
            for (int n = 0; n < 4; ++n)                                               \
                acc[m][n] = __builtin_amdgcn_mfma_f32_16x16x32_bf16(                  \
                    af[m], bfr[n], acc[m][n], 0, 0, 0);                               \
        __builtin_amdgcn_s_setprio(0);                                                \
        __builtin_amdgcn_sched_barrier(0);                                            \
        __builtin_amdgcn_s_barrier();                                                 \
    }

template <int EPI>
__global__ __launch_bounds__(256) void gemm128(
    const u16* __restrict__ A, const u16* __restrict__ Bt,
    const float* __restrict__ bias0, const float* __restrict__ bias1,
    const float* __restrict__ bias2,
    u16* __restrict__ o_q, u16* __restrict__ o_k, u16* __restrict__ o_vt,
    float* __restrict__ o_f, int nbx)
{
    __shared__ u16 As[2][128 * 32];   // 8 KB per buf; 64 B rows, swizzled chunks
    __shared__ u16 Bs[2][128 * 32];
    const int t = threadIdx.x;
    const int lane = t & 63, w = t >> 6;
    const int wm = w >> 1, wn = w & 1;
    const int g = lane >> 4, r = lane & 15;
    const int sv = (r & 3) ^ ((r >> 2) & 3);
    // bijective XCD swizzle (grid % 8 == 0)
    const int f = blockIdx.x;
    const int cpx = (gridDim.x >> 3);
    const int swz = (f & 7) * cpx + (f >> 3);
    const int mbase = (swz / nbx) * 128, nbase = (swz % nbx) * 128;

    const f32x4 zero4 = {0.f, 0.f, 0.f, 0.f};
    f32x4 acc[4][4];
#pragma unroll
    for (int m = 0; m < 4; ++m)
#pragma unroll
        for (int n = 0; n < 4; ++n) acc[m][n] = zero4;

    // prologue: stage tile 0 into buf 0 (4 gld16 in flight per wave)
#pragma unroll
    for (int i = 0; i < 2; ++i) {
        const int idx = i * 256 + t;
        const int row = idx >> 2, ch = idx & 3;
        const int chg = ch ^ ((row & 3) ^ ((row >> 2) & 3));
        gld16(A + (size_t)(mbase + row) * 1024 + chg * 8, (char*)&As[0][0] + idx * 16);
        gld16(Bt + (size_t)(nbase + row) * 1024 + chg * 8, (char*)&Bs[0][0] + idx * 16);
    }

    int k0 = 0;
    for (int s = 0; s < 15; ++s) {
        GEMM_STEP(0, k0 + 32, 1, 4) k0 += 32;
        GEMM_STEP(1, k0 + 32, 1, 4) k0 += 32;
    }
    GEMM_STEP(0, k0 + 32, 1, 4) k0 += 32;   // step 30 (stages step 31)
    GEMM_STEP(1, 0, 0, 0)                   // step 31 (drain own loads)

#pragma unroll
    for (int m = 0; m < 4; ++m) {
#pragma unroll
        for (int n = 0; n < 4; ++n) {
            const int c = nbase + wn * 64 + n * 16 + r;
#pragma unroll
            for (int j = 0; j < 4; ++j) {
                const int rr = mbase + wm * 64 + m * 16 + g * 4 + j;
                const float y = acc[m][n][j];
                if (EPI == 0) {
                    const int which = c >> 10, d = c & 1023;
                    const int b = rr >> 11, l = rr & 2047;
                    const int h = d >> 6, dd = d & 63;
                    const size_t bh = (size_t)(b * 16 + h);
                    if (which == 0) {
                        // Q pre-scale: 1/sqrt(64) * log2(e), so attn uses exp2 directly
                        o_q[(bh * 2048 + l) * 64 + dd] = f2bf((y + bias0[d]) * 0.18033688011112042f);
                    } else if (which == 1) {
                        o_k[(bh * 2048 + l) * 64 + dd] = f2bf(y + bias1[d]);
                    } else {
                        o_vt[(bh * 64 + dd) * 2048 + l] = f2bf(y + bias2[d]);
                    }
                } else {
                    o_f[(size_t)rr * 1024 + c] = y + bias0[c];
                }
            }
        }
    }
}

// ---------------- flash attention v11 (unchanged from R12) ----------------
// grid: 1024 flat. XCD x = flat&7 owns batch (x>>2), q-tiles (x&3)*8..+7, ALL 16 heads.
// block: 128 (2 waves x 32 q-rows). Counted vmcnt, raw barriers, no in-loop drain.

#define ATTN_STEP(CUR, BD, BDN, PREF, WAITN)                                                 \
    {                                                                                        \
        if (PREF) {                                                                          \
            const int kt2 = kt + 64;                                                         \
            _Pragma("unroll")                                                                \
            for (int i = 0; i < 4; ++i) {                                                    \
                const int idx = i * 128 + t;                                                 \
                const int row = idx >> 3, ch = idx & 7;                                      \
                const int chg = ch ^ (row & 7);                                              \
                gld16(kb + kvBase + (size_t)(kt2 + row) * 64 + chg * 8,                      \
                      (char*)&Ks[CUR ^ 1][0] + idx * 16);                                    \
                gld16(vtb + vtBase + (size_t)row * 2048 + kt2 + chg * 8,                     \
                      (char*)&Vs[CUR ^ 1][0] + idx * 16);                                    \
            }                                                                                \
            _Pragma("unroll")                                                                \
            for (int qf = 0; qf < 2; ++qf)                                                   \
                _Pragma("unroll")                                                            \
                for (int kf = 0; kf < 4; ++kf)                                               \
                    BDN[qf][kf] = *(const float4*)&bondf[bondRow0 + (size_t)qf * 32768 +     \
                                                         kt2 + kf * 16 + g * 4];             \
        }                                                                                    \
        asm volatile("s_waitcnt vmcnt(" #WAITN ")" ::: "memory");                            \
        __builtin_amdgcn_s_barrier();                                                        \
        __builtin_amdgcn_sched_barrier(0);                                                   \
        /* QK^T kf=0,1 */                                                                    \
        f32x4 st[2][4];                                                                      \
        {                                                                                    \
            bf16x8 kfr[2][2];                                                                \
            _Pragma("unroll")                                                                \
            for (int kz = 0; kz < 2; ++kz)                                                   \
                _Pragma("unroll")                                                            \
                for (int kf = 0; kf < 2; ++kf)                                               \
                    kfr[kz][kf] = *(const bf16x8*)((const char*)&Ks[CUR][0] +                \
                                    (kf * 16 + r) * 128 + (((kz * 4 + g) ^ sw) * 16));       \
            _Pragma("unroll")                                                                \
            for (int qf = 0; qf < 2; ++qf)                                                   \
                _Pragma("unroll")                                                            \
                for (int kf = 0; kf < 2; ++kf) st[qf][kf] = zero4;                           \
            __builtin_amdgcn_s_setprio(1);                                                   \
            _Pragma("unroll")                                                                \
            for (int kz = 0; kz < 2; ++kz)                                                   \
                _Pragma("unroll")                                                            \
                for (int qf = 0; qf < 2; ++qf)                                               \
                    _Pragma("unroll")                                                        \
                    for (int kf = 0; kf < 2; ++kf)                                           \
                        st[qf][kf] = __builtin_amdgcn_mfma_f32_16x16x32_bf16(                \
                            kfr[kz][kf], aq[qf][kz], st[qf][kf], 0, 0, 0);                   \
            __builtin_amdgcn_s_setprio(0);                                                   \
        }                                                                                    \
        /* exp kf=0,1 -> ap0 */                                                              \
        bf16x8 ap0[2], ap1[2];                                                               \
        _Pragma("unroll")                                                                    \
        for (int qf = 0; qf < 2; ++qf) {                                                     \
            uint32_t pkl[2], pkh[2];                                                         \
            _Pragma("unroll")                                                                \
            for (int kf = 0; kf < 2; ++kf) {                                                 \
                const float p0 = vexp2(st[qf][kf][0] * BD[qf][kf].x);                        \
                const float p1 = vexp2(st[qf][kf][1] * BD[qf][kf].y);                        \
                const float p2 = vexp2(st[qf][kf][2] * BD[qf][kf].z);                        \
                const float p3 = vexp2(st[qf][kf][3] * BD[qf][kf].w);                        \
                sm[qf] += (p0 + p1) + (p2 + p3);                                             \
                pkl[kf] = cvtpk(p0, p1);                                                     \
                pkh[kf] = cvtpk(p2, p3);                                                     \
            }                                                                                \
            plswap16(pkl[0], pkl[1]);                                                        \
            plswap16(pkh[0], pkh[1]);                                                        \
            union { uint32_t u[4]; bf16x8 v; } a_;                                           \
            a_.u[0] = pkl[0]; a_.u[1] = pkh[0]; a_.u[2] = pkl[1]; a_.u[3] = pkh[1];          \
            ap0[qf] = a_.v;                                                                  \
        }                                                                                    \
        /* QK^T kf=2,3 */                                                                    \
        {                                                                                    \
            bf16x8 kfr[2][2];                                                                \
            _Pragma("unroll")                                                                \
            for (int kz = 0; kz < 2; ++kz)                                                   \
                _Pragma("unroll")                                                            \
                for (int kf = 0; kf < 2; ++kf)                                               \
                    kfr[kz][kf] = *(const bf16x8*)((const char*)&Ks[CUR][0] +                \
                                    ((kf + 2) * 16 + r) * 128 + (((kz * 4 + g) ^ sw) * 16)); \
            _Pragma("unroll")                                                                \
            for (int qf = 0; qf < 2; ++qf)                                                   \
                _Pragma("unroll")                                                            \
                for (int kf = 0; kf < 2; ++kf) st[qf][kf + 2] = zero4;                       \
            __builtin_amdgcn_s_setprio(1);                                                   \
            _Pragma("unroll")                                                                \
            for (int kz = 0; kz < 2; ++kz)                                                   \
                _Pragma("unroll")                                                            \
                for (int qf = 0; qf < 2; ++qf)                                               \
                    _Pragma("unroll")                                                        \
                    for (int kf = 0; kf < 2; ++kf)                                           \
                        st[qf][kf + 2] = __builtin_amdgcn_mfma_f32_16x16x32_bf16(            \
                            kfr[kz][kf], aq[qf][kz], st[qf][kf + 2], 0, 0, 0);               \
            __builtin_amdgcn_s_setprio(0);                                                   \
        }                                                                                    \
        /* PV kz=0 */                                                                        \
        {                                                                                    \
            bf16x8 bv_[4];                                                                   \
            _Pragma("unroll")                                                                \
            for (int nf = 0; nf < 4; ++nf)                                                   \
                bv_[nf] = *(const bf16x8*)((const char*)&Vs[CUR][0] +                        \
                            (nf * 16 + r) * 128 + ((pg ^ sw) * 16));                         \
            __builtin_amdgcn_s_setprio(1);                                                   \
            _Pragma("unroll")                                                                \
            for (int qf = 0; qf < 2; ++qf)                                                   \
                _Pragma("unroll")                                                            \
                for (int nf = 0; nf < 4; ++nf)                                               \
                    o[qf][nf] = __builtin_amdgcn_mfma_f32_16x16x32_bf16(                     \
                        ap0[qf], bv_[nf], o[qf][nf], 0, 0, 0);                               \
            __builtin_amdgcn_s_setprio(0);                                                   \
        }                                                                                    \
        /* exp kf=2,3 -> ap1 */                                                              \
        _Pragma("unroll")                                                                    \
        for (int qf = 0; qf < 2; ++qf) {                                                     \
            uint32_t pkl[2], pkh[2];                                                         \
            _Pragma("unroll")                                                                \
            for (int kf = 0; kf < 2; ++kf) {                                                 \
                const float p0 = vexp2(st[qf][kf + 2][0] * BD[qf][kf + 2].x);                \
                const float p1 = vexp2(st[qf][kf + 2][1] * BD[qf][kf + 2].y);                \
                const float p2 = vexp2(st[qf][kf + 2][2] * BD[qf][kf + 2].z);                \
                const float p3 = vexp2(st[qf][kf + 2][3] * BD[qf][kf + 2].w);                \
                sm[qf] += (p0 + p1) + (p2 + p3);                                             \
                pkl[kf] = cvtpk(p0, p1);                                                     \
                pkh[kf] = cvtpk(p2, p3);                                                     \
            }                                                                                \
            plswap16(pkl[0], pkl[1]);                                                        \
            plswap16(pkh[0], pkh[1]);                                                        \
            union { uint32_t u[4]; bf16x8 v; } a_;                                           \
            a_.u[0] = pkl[0]; a_.u[1] = pkh[0]; a_.u[2] = pkl[1]; a_.u[3] = pkh[1];          \
            ap1[qf] = a_.v;                                                                  \
        }                                                                                    \
        /* PV kz=1 */                                                                        \
        {                                                                                    \
            bf16x8 bv_[4];                                                                   \
            _Pragma("unroll")                                                                \
            for (int nf = 0; nf < 4; ++nf)                                                   \
                bv_[nf] = *(const bf16x8*)((const char*)&Vs[CUR][0] +                        \
                            (nf * 16 + r) * 128 + (((4 + pg) ^ sw) * 16));                   \
            __builtin_amdgcn_s_setprio(1);                                                   \
            _Pragma("unroll")                                                                \
            for (int qf = 0; qf < 2; ++qf)                                                   \
                _Pragma("unroll")                                                            \
                for (int nf = 0; nf < 4; ++nf)                                               \
                    o[qf][nf] = __builtin_amdgcn_mfma_f32_16x16x32_bf16(                     \
                        ap1[qf], bv_[nf], o[qf][nf], 0, 0, 0);                               \
            __builtin_amdgcn_s_setprio(0);                                                   \
        }                                                                                    \
        __builtin_amdgcn_sched_barrier(0);                                                   \
        __builtin_amdgcn_s_barrier();                                                        \
        kt += 64;                                                                            \
    }

__global__ __launch_bounds__(128, 2) void attn_kernel(
    const u16* __restrict__ qb, const u16* __restrict__ kb,
    const u16* __restrict__ vtb, const float* __restrict__ bondf,
    u16* __restrict__ attnout)
{
    __shared__ u16 Ks[2][64 * 64];   // [buf][key][dk]   swizzled chunks
    __shared__ u16 Vs[2][64 * 64];   // [buf][dk][key]   swizzled chunks
    const int t = threadIdx.x;
    const int lane = t & 63, w = t >> 6;
    const int g = lane >> 4, r = lane & 15;
    const int sw = r & 7;
    const int pg = ((g & 1) << 1) | (g >> 1);   // key-chunk permutation from permlane16_swap
    const int flat = blockIdx.x;
    const int x = flat & 7;          // XCD (dispatch round-robin)
    const int j = flat >> 3;         // 0..127 within XCD
    const int b = x >> 2;
    const int qt = (x & 3) * 8 + (j & 7);
    const int h = j >> 3;
    const int bh = b * 16 + h;
    const int q0 = qt * 64 + w * 32;
    const size_t kvBase = (size_t)bh * 2048 * 64;
    const size_t vtBase = (size_t)bh * 64 * 2048;
    const size_t bondRow0 = ((size_t)b * 2048 + q0 + r) * 2048;   // qf adds 32768

    // Q as B-operand fragments (pre-scaled by 1/8*log2e in the QKV epilogue)
    bf16x8 aq[2][2];
#pragma unroll
    for (int qf = 0; qf < 2; ++qf)
#pragma unroll
        for (int kz = 0; kz < 2; ++kz)
            aq[qf][kz] = *(const bf16x8*)&qb[kvBase + (size_t)(q0 + qf * 16 + r) * 64 + kz * 32 + g * 8];

    const f32x4 zero4 = {0.f, 0.f, 0.f, 0.f};
    f32x4 o[2][4];
#pragma unroll
    for (int qf = 0; qf < 2; ++qf)
#pragma unroll
        for (int nf = 0; nf < 4; ++nf) o[qf][nf] = zero4;
    float sm[2] = {0.f, 0.f};

    // prologue: stage K/V tile 0; bond tile 0 into bdA regs (16 vmem in flight)
#pragma unroll
    for (int i = 0; i < 4; ++i) {
        const int idx = i * 128 + t;
        const int row = idx >> 3, ch = idx & 7;
        const int chg = ch ^ (row & 7);
        gld16(kb + kvBase + (size_t)row * 64 + chg * 8, (char*)&Ks[0][0] + idx * 16);
        gld16(vtb + vtBase + (size_t)row * 2048 + chg * 8, (char*)&Vs[0][0] + idx * 16);
    }
    float4 bdA[2][4], bdB[2][4];
#pragma unroll
    for (int qf = 0; qf < 2; ++qf)
#pragma unroll
        for (int kf = 0; kf < 4; ++kf)
            bdA[qf][kf] = *(const float4*)&bondf[bondRow0 + (size_t)qf * 32768 + kf * 16 + g * 4];

    int kt = 0;
    for (int s = 0; s < 15; ++s) {
        ATTN_STEP(0, bdA, bdB, 1, 16)   // iters 0,2,..,28
        ATTN_STEP(1, bdB, bdA, 1, 16)   // iters 1,3,..,29
    }
    ATTN_STEP(0, bdA, bdB, 1, 16)       // iter 30 (stages tile 31)
    ATTN_STEP(1, bdB, bdA, 0, 0)        // iter 31 (drain)

    // row sums: reduce across the 4 g-groups, redistribute via width-16 shuffle
#pragma unroll
    for (int qf = 0; qf < 2; ++qf) {
        sm[qf] += __shfl_xor(sm[qf], 16, 64);
        sm[qf] += __shfl_xor(sm[qf], 32, 64);
    }
#pragma unroll
    for (int qf = 0; qf < 2; ++qf)
#pragma unroll
        for (int j2 = 0; j2 < 4; ++j2) {
            const float inv = 1.f / __shfl(sm[qf], g * 4 + j2, 16);
            const size_t orow = ((size_t)b * 2048 + q0 + qf * 16 + g * 4 + j2) * 1024 + h * 64;
#pragma unroll
            for (int nf = 0; nf < 4; ++nf)
                attnout[orow + nf * 16 + r] = f2bf(o[qf][nf][j2] * inv);
        }
}

// ---------------- launch ----------------

extern "C" void kernel_launch(void* const* d_in, const int* in_sizes, int n_in,
                              void* d_out, int out_size, void* d_ws, size_t ws_size,
                              hipStream_t stream) {
    (void)in_sizes; (void)n_in; (void)out_size; (void)ws_size;
    const float* x    = (const float*)d_in[0];
    const float* bond = (const float*)d_in[1];
    const float* Wq   = (const float*)d_in[2];
    const float* bq   = (const float*)d_in[3];
    const float* Wk   = (const float*)d_in[4];
    const float* bk   = (const float*)d_in[5];
    const float* Wv   = (const float*)d_in[6];
    const float* bv   = (const float*)d_in[7];
    const float* Wo   = (const float*)d_in[8];
    const float* bo   = (const float*)d_in[9];
    float* out = (float*)d_out;

    char* ws = (char*)d_ws;
    u16* xb      = (u16*)(ws);
    u16* wqkvt   = (u16*)(ws + 8388608);
    u16* wot     = (u16*)(ws + 14680064);
    u16* qb      = (u16*)(ws + 16777216);
    u16* kb_     = (u16*)(ws + 25165824);
    u16* vtb     = (u16*)(ws + 33554432);
    u16* attnout = (u16*)(ws + 58720256);

    pack5_kernel<<<dim3(32, 32, 5), dim3(32, 8), 0, stream>>>(Wq, Wk, Wv, Wo, x, wqkvt, wot, xb);

    gemm128<0><<<dim3(768), 256, 0, stream>>>(xb, wqkvt, bq, bk, bv, qb, kb_, vtb, nullptr, 24);
    attn_kernel<<<dim3(1024), 128, 0, stream>>>(qb, kb_, vtb, bond, attnout);
    gemm128<1><<<dim3(256), 256, 0, stream>>>(attnout, wot, bo, nullptr, nullptr,
                                              nullptr, nullptr, nullptr, out, 8);
}

// Round 16
// 153.090 us; speedup vs baseline: 1.1517x; 1.0392x over previous
//
#include <hip/hip_runtime.h>
#include <stdint.h>

typedef unsigned short u16;
typedef __attribute__((ext_vector_type(8))) short bf16x8;
typedef __attribute__((ext_vector_type(4))) float f32x4;

__device__ __forceinline__ u16 f2bf(float f) {
    union { float f; uint32_t u; } v; v.f = f;
    uint32_t u = v.u + 0x7fffu + ((v.u >> 16) & 1u);
    return (u16)(u >> 16);
}
// hardware 2^x
__device__ __forceinline__ float vexp2(float x) {
    float d;
    asm("v_exp_f32 %0, %1" : "=v"(d) : "v"(x));
    return d;
}
// packed f32x2 -> bf16x2 (hardware round)
__device__ __forceinline__ uint32_t cvtpk(float a, float b) {
    uint32_t d;
    asm("v_cvt_pk_bf16_f32 %0, %1, %2" : "=v"(d) : "v"(a), "v"(b));
    return d;
}

__device__ __forceinline__ void gld16(const void* g, void* l) {
    __builtin_amdgcn_global_load_lds((const __attribute__((address_space(1))) void*)g,
                                     (__attribute__((address_space(3))) void*)l,
                                     16, 0, 0);
}

// in-place cross-lane swap: a.row1<->b.row0, a.row3<->b.row2 (rows = 16-lane groups)
__device__ __forceinline__ void plswap16(uint32_t& a, uint32_t& b) {
    asm volatile("v_permlane16_swap_b32 %0, %1" : "+v"(a), "+v"(b));
}

// ---------------- fused pack kernel: 4 weight transposes + x cvt ----------------
// grid (32,32,5), block (32,8). z<4: transpose W_z. z==4: x fp32->bf16 stream.

__global__ void pack5_kernel(const float* __restrict__ Wq, const float* __restrict__ Wk,
                             const float* __restrict__ Wv, const float* __restrict__ Wo,
                             const float* __restrict__ x,
                             u16* __restrict__ dqkv, u16* __restrict__ dwo,
                             u16* __restrict__ dx) {
    const int z = blockIdx.z;
    const int tx = threadIdx.x, ty = threadIdx.y;
    if (z == 4) {
        // x cvt: 1024 blocks x 1024 float4
        const int bid = blockIdx.y * 32 + blockIdx.x;
        const int tid = ty * 32 + tx;
#pragma unroll
        for (int i = 0; i < 4; ++i) {
            const int idx = bid * 1024 + i * 256 + tid;
            float4 v = ((const float4*)x)[idx];
            ushort4 o;
            o.x = f2bf(v.x); o.y = f2bf(v.y); o.z = f2bf(v.z); o.w = f2bf(v.w);
            ((ushort4*)dx)[idx] = o;
        }
        return;
    }
    __shared__ float tile[32][33];
    const float* src = (z == 0) ? Wq : (z == 1) ? Wk : (z == 2) ? Wv : Wo;
    u16* dst = (z < 3) ? (dqkv + (size_t)z * 1024 * 1024) : dwo;
    const int bx = blockIdx.x * 32, by = blockIdx.y * 32;
#pragma unroll
    for (int i = ty; i < 32; i += 8)
        tile[i][tx] = src[(size_t)(by + i) * 1024 + bx + tx];
    __syncthreads();
#pragma unroll
    for (int i = ty; i < 32; i += 8)
        dst[(size_t)(bx + i) * 1024 + by + tx] = f2bf(tile[tx][i]);
}

// ---------------- GEMM (128x128 tile, BK=64, 4 waves, XOR-swizzled LDS) ----------------
// 1D grid with bijective XCD swizzle. NBX = N/128 column-blocks.

template <int EPI>
__global__ __launch_bounds__(256) void gemm128(
    const u16* __restrict__ A, const u16* __restrict__ Bt,
    const float* __restrict__ bias0, const float* __restrict__ bias1,
    const float* __restrict__ bias2,
    u16* __restrict__ o_q, u16* __restrict__ o_k, u16* __restrict__ o_vt,
    float* __restrict__ o_f, int nbx)
{
    constexpr int K = 1024;
    __shared__ u16 As[128 * 64];   // rows of 128 B, swizzle: ch ^ (row&7)
    __shared__ u16 Bs[128 * 64];
    const int t = threadIdx.x;
    const int lane = t & 63, w = t >> 6;
    const int wm = w >> 1, wn = w & 1;
    const int g = lane >> 4, r = lane & 15;
    const int sw = r & 7;
    // bijective XCD swizzle (grid % 8 == 0)
    const int f = blockIdx.x;
    const int cpx = (gridDim.x >> 3);
    const int swz = (f & 7) * cpx + (f >> 3);
    const int mbase = (swz / nbx) * 128, nbase = (swz % nbx) * 128;

    const f32x4 zero4 = {0.f, 0.f, 0.f, 0.f};
    f32x4 acc[4][4];
#pragma unroll
    for (int m = 0; m < 4; ++m)
#pragma unroll
        for (int n = 0; n < 4; ++n) acc[m][n] = zero4;

    for (int k0 = 0; k0 < K; k0 += 64) {
#pragma unroll
        for (int i = 0; i < 4; ++i) {
            const int idx = i * 256 + t;
            const int row = idx >> 3, ch = idx & 7;
            const int chg = ch ^ (row & 7);
            gld16(A + (size_t)(mbase + row) * K + k0 + chg * 8, (char*)As + idx * 16);
            gld16(Bt + (size_t)(nbase + row) * K + k0 + chg * 8, (char*)Bs + idx * 16);
        }
        __syncthreads();

#pragma unroll
        for (int kk = 0; kk < 2; ++kk) {
            bf16x8 af[4], bfr[4];
#pragma unroll
            for (int m = 0; m < 4; ++m) {
                const int row = wm * 64 + m * 16 + r;
                af[m] = *(const bf16x8*)((const char*)As + row * 128 + (((kk * 4 + g) ^ sw) << 4));
            }
#pragma unroll
            for (int n = 0; n < 4; ++n) {
                const int row = wn * 64 + n * 16 + r;
                bfr[n] = *(const bf16x8*)((const char*)Bs + row * 128 + (((kk * 4 + g) ^ sw) << 4));
            }
            __builtin_amdgcn_s_setprio(1);
#pragma unroll
            for (int m = 0; m < 4; ++m)
#pragma unroll
                for (int n = 0; n < 4; ++n)
                    acc[m][n] = __builtin_amdgcn_mfma_f32_16x16x32_bf16(af[m], bfr[n], acc[m][n], 0, 0, 0);
            __builtin_amdgcn_s_setprio(0);
        }
        __syncthreads();
    }

#pragma unroll
    for (int m = 0; m < 4; ++m) {
#pragma unroll
        for (int n = 0; n < 4; ++n) {
            const int c = nbase + wn * 64 + n * 16 + r;
#pragma unroll
            for (int j = 0; j < 4; ++j) {
                const int rr = mbase + wm * 64 + m * 16 + g * 4 + j;
                const float y = acc[m][n][j];
                if (EPI == 0) {
                    const int which = c >> 10, d = c & 1023;
                    const int b = rr >> 11, l = rr & 2047;
                    const int h = d >> 6, dd = d & 63;
                    const size_t bh = (size_t)(b * 16 + h);
                    if (which == 0) {
                        // Q pre-scale: 1/sqrt(64) * log2(e), so attn uses exp2 directly
                        o_q[(bh * 2048 + l) * 64 + dd] = f2bf((y + bias0[d]) * 0.18033688011112042f);
                    } else if (which == 1) {
                        o_k[(bh * 2048 + l) * 64 + dd] = f2bf(y + bias1[d]);
                    } else {
                        o_vt[(bh * 64 + dd) * 2048 + l] = f2bf(y + bias2[d]);
                    }
                } else {
                    o_f[(size_t)rr * 1024 + c] = y + bias0[c];
                }
            }
        }
    }
}

// ---------------- flash attention v11 (unchanged from R12) ----------------
// grid: 1024 flat. XCD x = flat&7 owns batch (x>>2), q-tiles (x&3)*8..+7, ALL 16 heads.
// block: 128 (2 waves x 32 q-rows). Counted vmcnt, raw barriers, no in-loop drain.

#define ATTN_STEP(CUR, BD, BDN, PREF, WAITN)                                                 \
    {                                                                                        \
        if (PREF) {                                                                          \
            const int kt2 = kt + 64;                                                         \
            _Pragma("unroll")                                                                \
            for (int i = 0; i < 4; ++i) {                                                    \
                const int idx = i * 128 + t;                                                 \
                const int row = idx >> 3, ch = idx & 7;                                      \
                const int chg = ch ^ (row & 7);                                              \
                gld16(kb + kvBase + (size_t)(kt2 + row) * 64 + chg * 8,                      \
                      (char*)&Ks[CUR ^ 1][0] + idx * 16);                                    \
                gld16(vtb + vtBase + (size_t)row * 2048 + kt2 + chg * 8,                     \
                      (char*)&Vs[CUR ^ 1][0] + idx * 16);                                    \
            }                                                                                \
            _Pragma("unroll")                                                                \
            for (int qf = 0; qf < 2; ++qf)                                                   \
                _Pragma("unroll")                                                            \
                for (int kf = 0; kf < 4; ++kf)                                               \
                    BDN[qf][kf] = *(const float4*)&bondf[bondRow0 + (size_t)qf * 32768 +     \
                                                         kt2 + kf * 16 + g * 4];             \
        }                                                                                    \
        asm volatile("s_waitcnt vmcnt(" #WAITN ")" ::: "memory");                            \
        __builtin_amdgcn_s_barrier();                                                        \
        __builtin_amdgcn_sched_barrier(0);                                                   \
        /* QK^T kf=0,1 */                                                                    \
        f32x4 st[2][4];                                                                      \
        {                                                                                    \
            bf16x8 kfr[2][2];                                                                \
            _Pragma("unroll")                                                                \
            for (int kz = 0; kz < 2; ++kz)                                                   \
                _Pragma("unroll")                                                            \
                for (int kf = 0; kf < 2; ++kf)                                               \
                    kfr[kz][kf] = *(const bf16x8*)((const char*)&Ks[CUR][0] +                \
                                    (kf * 16 + r) * 128 + (((kz * 4 + g) ^ sw) * 16));       \
            _Pragma("unroll")                                                                \
            for (int qf = 0; qf < 2; ++qf)                                                   \
                _Pragma("unroll")                                                            \
                for (int kf = 0; kf < 2; ++kf) st[qf][kf] = zero4;                           \
            __builtin_amdgcn_s_setprio(1);                                                   \
            _Pragma("unroll")                                                                \
            for (int kz = 0; kz < 2; ++kz)                                                   \
                _Pragma("unroll")                                                            \
                for (int qf = 0; qf < 2; ++qf)                                               \
                    _Pragma("unroll")                                                        \
                    for (int kf = 0; kf < 2; ++kf)                                           \
                        st[qf][kf] = __builtin_amdgcn_mfma_f32_16x16x32_bf16(                \
                            kfr[kz][kf], aq[qf][kz], st[qf][kf], 0, 0, 0);                   \
            __builtin_amdgcn_s_setprio(0);                                                   \
        }                                                                                    \
        /* exp kf=0,1 -> ap0 */                                                              \
        bf16x8 ap0[2], ap1[2];                                                               \
        _Pragma("unroll")                                                                    \
        for (int qf = 0; qf < 2; ++qf) {                                                     \
            uint32_t pkl[2], pkh[2];                                                         \
            _Pragma("unroll")                                                                \
            for (int kf = 0; kf < 2; ++kf) {                                                 \
                const float p0 = vexp2(st[qf][kf][0] * BD[qf][kf].x);                        \
                const float p1 = vexp2(st[qf][kf][1] * BD[qf][kf].y);                        \
                const float p2 = vexp2(st[qf][kf][2] * BD[qf][kf].z);                        \
                const float p3 = vexp2(st[qf][kf][3] * BD[qf][kf].w);                        \
                sm[qf] += (p0 + p1) + (p2 + p3);                                             \
                pkl[kf] = cvtpk(p0, p1);                                                     \
                pkh[kf] = cvtpk(p2, p3);                                                     \
            }                                                                                \
            plswap16(pkl[0], pkl[1]);                                                        \
            plswap16(pkh[0], pkh[1]);                                                        \
            union { uint32_t u[4]; bf16x8 v; } a_;                                           \
            a_.u[0] = pkl[0]; a_.u[1] = pkh[0]; a_.u[2] = pkl[1]; a_.u[3] = pkh[1];          \
            ap0[qf] = a_.v;                                                                  \
        }                                                                                    \
        /* QK^T kf=2,3 */                                                                    \
        {                                                                                    \
            bf16x8 kfr[2][2];                                                                \
            _Pragma("unroll")                                                                \
            for (int kz = 0; kz < 2; ++kz)                                                   \
                _Pragma("unroll")                                                            \
                for (int kf = 0; kf < 2; ++kf)                                               \
                    kfr[kz][kf] = *(const bf16x8*)((const char*)&Ks[CUR][0] +                \
                                    ((kf + 2) * 16 + r) * 128 + (((kz * 4 + g) ^ sw) * 16)); \
            _Pragma("unroll")                                                                \
            for (int qf = 0; qf < 2; ++qf)                                                   \
                _Pragma("unroll")                                                            \
                for (int kf = 0; kf < 2; ++kf) st[qf][kf + 2] = zero4;                       \
            __builtin_amdgcn_s_setprio(1);                                                   \
            _Pragma("unroll")                                                                \
            for (int kz = 0; kz < 2; ++kz)                                                   \
                _Pragma("unroll")                                                            \
                for (int qf = 0; qf < 2; ++qf)                                               \
                    _Pragma("unroll")                                                        \
                    for (int kf = 0; kf < 2; ++kf)                                           \
                        st[qf][kf + 2] = __builtin_amdgcn_mfma_f32_16x16x32_bf16(            \
                            kfr[kz][kf], aq[qf][kz], st[qf][kf + 2], 0, 0, 0);               \
            __builtin_amdgcn_s_setprio(0);                                                   \
        }                                                                                    \
        /* PV kz=0 */                                                                        \
        {                                                                                    \
            bf16x8 bv_[4];                                                                   \
            _Pragma("unroll")                                                                \
            for (int nf = 0; nf < 4; ++nf)                                                   \
                bv_[nf] = *(const bf16x8*)((const char*)&Vs[CUR][0] +                        \
                            (nf * 16 + r) * 128 + ((pg ^ sw) * 16));                         \
            __builtin_amdgcn_s_setprio(1);                                                   \
            _Pragma("unroll")                                                                \
            for (int qf = 0; qf < 2; ++qf)                                                   \
                _Pragma("unroll")                                                            \
                for (int nf = 0; nf < 4; ++nf)                                               \
                    o[qf][nf] = __builtin_amdgcn_mfma_f32_16x16x32_bf16(                     \
                        ap0[qf], bv_[nf], o[qf][nf], 0, 0, 0);                               \
            __builtin_amdgcn_s_setprio(0);                                                   \
        }                                                                                    \
        /* exp kf=2,3 -> ap1 */                                                              \
        _Pragma("unroll")                                                                    \
        for (int qf = 0; qf < 2; ++qf) {                                                     \
            uint32_t pkl[2], pkh[2];                                                         \
            _Pragma("unroll")                                                                \
            for (int kf = 0; kf < 2; ++kf) {                                                 \
                const float p0 = vexp2(st[qf][kf + 2][0] * BD[qf][kf + 2].x);                \
                const float p1 = vexp2(st[qf][kf + 2][1] * BD[qf][kf + 2].y);                \
                const float p2 = vexp2(st[qf][kf + 2][2] * BD[qf][kf + 2].z);                \
                const float p3 = vexp2(st[qf][kf + 2][3] * BD[qf][kf + 2].w);                \
                sm[qf] += (p0 + p1) + (p2 + p3);                                             \
                pkl[kf] = cvtpk(p0, p1);                                                     \
                pkh[kf] = cvtpk(p2, p3);                                                     \
            }                                                                                \
            plswap16(pkl[0], pkl[1]);                                                        \
            plswap16(pkh[0], pkh[1]);                                                        \
            union { uint32_t u[4]; bf16x8 v; } a_;                                           \
            a_.u[0] = pkl[0]; a_.u[1] = pkh[0]; a_.u[2] = pkl[1]; a_.u[3] = pkh[1];          \
            ap1[qf] = a_.v;                                                                  \
        }                                                                                    \
        /* PV kz=1 */                                                                        \
        {                                                                                    \
            bf16x8 bv_[4];                                                                   \
            _Pragma("unroll")                                                                \
            for (int nf = 0; nf < 4; ++nf)                                                   \
                bv_[nf] = *(const bf16x8*)((const char*)&Vs[CUR][0] +                        \
                            (nf * 16 + r) * 128 + (((4 + pg) ^ sw) * 16));                   \
            __builtin_amdgcn_s_setprio(1);                                                   \
            _Pragma("unroll")                                                                \
            for (int qf = 0; qf < 2; ++qf)                                                   \
                _Pragma("unroll")                                                            \
                for (int nf = 0; nf < 4; ++nf)                                               \
                    o[qf][nf] = __builtin_amdgcn_mfma_f32_16x16x32_bf16(                     \
                        ap1[qf], bv_[nf], o[qf][nf], 0, 0, 0);                               \
            __builtin_amdgcn_s_setprio(0);                                                   \
        }                                                                                    \
        __builtin_amdgcn_sched_barrier(0);                                                   \
        __builtin_amdgcn_s_barrier();                                                        \
        kt += 64;                                                                            \
    }

__global__ __launch_bounds__(128, 2) void attn_kernel(
    const u16* __restrict__ qb, const u16* __restrict__ kb,
    const u16* __restrict__ vtb, const float* __restrict__ bondf,
    u16* __restrict__ attnout)
{
    __shared__ u16 Ks[2][64 * 64];   // [buf][key][dk]   swizzled chunks
    __shared__ u16 Vs[2][64 * 64];   // [buf][dk][key]   swizzled chunks
    const int t = threadIdx.x;
    const int lane = t & 63, w = t >> 6;
    const int g = lane >> 4, r = lane & 15;
    const int sw = r & 7;
    const int pg = ((g & 1) << 1) | (g >> 1);   // key-chunk permutation from permlane16_swap
    const int flat = blockIdx.x;
    const int x = flat & 7;          // XCD (dispatch round-robin)
    const int j = flat >> 3;         // 0..127 within XCD
    const int b = x >> 2;
    const int qt = (x & 3) * 8 + (j & 7);
    const int h = j >> 3;
    const int bh = b * 16 + h;
    const int q0 = qt * 64 + w * 32;
    const size_t kvBase = (size_t)bh * 2048 * 64;
    const size_t vtBase = (size_t)bh * 64 * 2048;
    const size_t bondRow0 = ((size_t)b * 2048 + q0 + r) * 2048;   // qf adds 32768

    // Q as B-operand fragments (pre-scaled by 1/8*log2e in the QKV epilogue)
    bf16x8 aq[2][2];
#pragma unroll
    for (int qf = 0; qf < 2; ++qf)
#pragma unroll
        for (int kz = 0; kz < 2; ++kz)
            aq[qf][kz] = *(const bf16x8*)&qb[kvBase + (size_t)(q0 + qf * 16 + r) * 64 + kz * 32 + g * 8];

    const f32x4 zero4 = {0.f, 0.f, 0.f, 0.f};
    f32x4 o[2][4];
#pragma unroll
    for (int qf = 0; qf < 2; ++qf)
#pragma unroll
        for (int nf = 0; nf < 4; ++nf) o[qf][nf] = zero4;
    float sm[2] = {0.f, 0.f};

    // prologue: stage K/V tile 0; bond tile 0 into bdA regs (16 vmem in flight)
#pragma unroll
    for (int i = 0; i < 4; ++i) {
        const int idx = i * 128 + t;
        const int row = idx >> 3, ch = idx & 7;
        const int chg = ch ^ (row & 7);
        gld16(kb + kvBase + (size_t)row * 64 + chg * 8, (char*)&Ks[0][0] + idx * 16);
        gld16(vtb + vtBase + (size_t)row * 2048 + chg * 8, (char*)&Vs[0][0] + idx * 16);
    }
    float4 bdA[2][4], bdB[2][4];
#pragma unroll
    for (int qf = 0; qf < 2; ++qf)
#pragma unroll
        for (int kf = 0; kf < 4; ++kf)
            bdA[qf][kf] = *(const float4*)&bondf[bondRow0 + (size_t)qf * 32768 + kf * 16 + g * 4];

    int kt = 0;
    for (int s = 0; s < 15; ++s) {
        ATTN_STEP(0, bdA, bdB, 1, 16)   // iters 0,2,..,28
        ATTN_STEP(1, bdB, bdA, 1, 16)   // iters 1,3,..,29
    }
    ATTN_STEP(0, bdA, bdB, 1, 16)       // iter 30 (stages tile 31)
    ATTN_STEP(1, bdB, bdA, 0, 0)        // iter 31 (drain)

    // row sums: reduce across the 4 g-groups, redistribute via width-16 shuffle
#pragma unroll
    for (int qf = 0; qf < 2; ++qf) {
        sm[qf] += __shfl_xor(sm[qf], 16, 64);
        sm[qf] += __shfl_xor(sm[qf], 32, 64);
    }
#pragma unroll
    for (int qf = 0; qf < 2; ++qf)
#pragma unroll
        for (int j2 = 0; j2 < 4; ++j2) {
            const float inv = 1.f / __shfl(sm[qf], g * 4 + j2, 16);
            const size_t orow = ((size_t)b * 2048 + q0 + qf * 16 + g * 4 + j2) * 1024 + h * 64;
#pragma unroll
            for (int nf = 0; nf < 4; ++nf)
                attnout[orow + nf * 16 + r] = f2bf(o[qf][nf][j2] * inv);
        }
}

// ---------------- launch ----------------

extern "C" void kernel_launch(void* const* d_in, const int* in_sizes, int n_in,
                              void* d_out, int out_size, void* d_ws, size_t ws_size,
                              hipStream_t stream) {
    (void)in_sizes; (void)n_in; (void)out_size; (void)ws_size;
    const float* x    = (const float*)d_in[0];
    const float* bond = (const float*)d_in[1];
    const float* Wq   = (const float*)d_in[2];
    const float* bq   = (const float*)d_in[3];
    const float* Wk   = (const float*)d_in[4];
    const float* bk   = (const float*)d_in[5];
    const float* Wv   = (const float*)d_in[6];
    const float* bv   = (const float*)d_in[7];
    const float* Wo   = (const float*)d_in[8];
    const float* bo   = (const float*)d_in[9];
    float* out = (float*)d_out;

    char* ws = (char*)d_ws;
    u16* xb      = (u16*)(ws);
    u16* wqkvt   = (u16*)(ws + 8388608);
    u16* wot     = (u16*)(ws + 14680064);
    u16* qb      = (u16*)(ws + 16777216);
    u16* kb_     = (u16*)(ws + 25165824);
    u16* vtb     = (u16*)(ws + 33554432);
    u16* attnout = (u16*)(ws + 58720256);

    pack5_kernel<<<dim3(32, 32, 5), dim3(32, 8), 0, stream>>>(Wq, Wk, Wv, Wo, x, wqkvt, wot, xb);

    gemm128<0><<<dim3(768), 256, 0, stream>>>(xb, wqkvt, bq, bk, bv, qb, kb_, vtb, nullptr, 24);
    attn_kernel<<<dim3(1024), 128, 0, stream>>>(qb, kb_, vtb, bond, attnout);
    gemm128<1><<<dim3(256), 256, 0, stream>>>(attnout, wot, bo, nullptr, nullptr,
                                              nullptr, nullptr, nullptr, out, 8);
}